// Round 2
// 1722.198 us; speedup vs baseline: 1.9681x; 1.9681x over previous
//
#include <hip/hip_runtime.h>

// Problem constants (B=16, S=512, D=1024, H=16, DK=64)
#define SEQ    512
#define NH     16
#define HDIM   64
#define DMODEL 1024
#define MROWS  8192              // B*S
#define OUT_ELEMS   8388608ll   // B*S*D
#define ATTN_ELEMS  67108864ll  // B*H*S*S

typedef __attribute__((ext_vector_type(8))) short short8;  // 8 bf16 (4 VGPRs)
typedef __attribute__((ext_vector_type(4))) float f32x4;   // MFMA accumulator

// ---- fp32 -> bf16 split helpers (RNE) ---------------------------------------
__device__ __forceinline__ ushort f2bf(float x) {
    unsigned u = __float_as_uint(x);
    u += 0x7FFFu + ((u >> 16) & 1u);          // round-to-nearest-even
    return (ushort)(u >> 16);
}
__device__ __forceinline__ float bf2f(ushort h) {
    return __uint_as_float(((unsigned)h) << 16);
}
__device__ __forceinline__ unsigned pack2(ushort a, ushort b) {
    return (unsigned)a | ((unsigned)b << 16);
}

// ---------------------------------------------------------------------------
// split_kernel: X fp32 [count] -> hi/lo bf16 same layout. 8 elems/thread.
// ---------------------------------------------------------------------------
__global__ __launch_bounds__(256)
void split_kernel(const float* __restrict__ X, ushort* __restrict__ hi,
                  ushort* __restrict__ lo)
{
    size_t base = ((size_t)blockIdx.x * 256 + threadIdx.x) * 8;
    float4 x0 = *(const float4*)&X[base];
    float4 x1 = *(const float4*)&X[base + 4];
    float xs[8] = {x0.x, x0.y, x0.z, x0.w, x1.x, x1.y, x1.z, x1.w};
    ushort h[8], l[8];
#pragma unroll
    for (int i = 0; i < 8; ++i) {
        h[i] = f2bf(xs[i]);
        l[i] = f2bf(xs[i] - bf2f(h[i]));
    }
    uint4 uh, ul;
    uh.x = pack2(h[0], h[1]); uh.y = pack2(h[2], h[3]);
    uh.z = pack2(h[4], h[5]); uh.w = pack2(h[6], h[7]);
    ul.x = pack2(l[0], l[1]); ul.y = pack2(l[2], l[3]);
    ul.z = pack2(l[4], l[5]); ul.w = pack2(l[6], l[7]);
    *(uint4*)&hi[base] = uh;
    *(uint4*)&lo[base] = ul;
}

// ---------------------------------------------------------------------------
// splitT_kernel: W fp32 [K][N] -> Wt hi/lo bf16 [N][K] (transpose + split).
// Block = 64 cols x 64 ks; thread: 1 col, 16 consecutive k (strided reads are
// wave-coalesced across 64 consecutive cols; writes are 2x uint4 per array).
// ---------------------------------------------------------------------------
__global__ __launch_bounds__(256)
void splitT_kernel(const float* __restrict__ W, ushort* __restrict__ th,
                   ushort* __restrict__ tl, int N, int K)
{
    const int t   = threadIdx.x;
    const int col = blockIdx.x * 64 + (t & 63);
    const int kb  = blockIdx.y * 64 + (t >> 6) * 16;
    ushort h[16], l[16];
#pragma unroll
    for (int i = 0; i < 16; ++i) {
        float x = W[(size_t)(kb + i) * N + col];
        h[i] = f2bf(x);
        l[i] = f2bf(x - bf2f(h[i]));
    }
    size_t o = (size_t)col * K + kb;
    uint4 u;
    u.x = pack2(h[0], h[1]);  u.y = pack2(h[2], h[3]);
    u.z = pack2(h[4], h[5]);  u.w = pack2(h[6], h[7]);
    *(uint4*)&th[o] = u;
    u.x = pack2(h[8], h[9]);  u.y = pack2(h[10], h[11]);
    u.z = pack2(h[12], h[13]); u.w = pack2(h[14], h[15]);
    *(uint4*)&th[o + 8] = u;
    u.x = pack2(l[0], l[1]);  u.y = pack2(l[2], l[3]);
    u.z = pack2(l[4], l[5]);  u.w = pack2(l[6], l[7]);
    *(uint4*)&tl[o] = u;
    u.x = pack2(l[8], l[9]);  u.y = pack2(l[10], l[11]);
    u.z = pack2(l[12], l[13]); u.w = pack2(l[14], l[15]);
    *(uint4*)&tl[o + 8] = u;
}

// ---------------------------------------------------------------------------
// gemm_mfma: C = A[M,K] @ B[K,N] + bias, fp32-emulated via bf16x3 MFMA.
//   A pre-split: Ahi/Alo bf16 [M][K]; B pre-split+transposed: Bhi/Blo [N][K].
//   acc += Ah*Bh + Al*Bh + Ah*Bl  (lo*lo dropped; rel err ~2^-16)
// 128x128 tile, BK=32, 4 waves (2x2), 4x4 16x16x32 fragments per wave.
// Scatter-store identical to previous gemm_nn (Hn/cl scheme).
// LDS rows padded to 40 bf16 (80 B): frag reads & staged writes both land
// 8 lanes per 16B-bank-group (balanced, conflict-free in aggregate).
// ---------------------------------------------------------------------------
__global__ __launch_bounds__(256)
void gemm_mfma(const ushort* __restrict__ Ahi, const ushort* __restrict__ Alo,
               const ushort* __restrict__ Bhi, const ushort* __restrict__ Blo,
               const float* __restrict__ bias, float* __restrict__ Cdst,
               int K, int Hn, int cl)
{
    __shared__ ushort sA[2][128][40];   // [hi/lo][row][k]
    __shared__ ushort sB[2][128][40];   // [hi/lo][col][k]

    const int t    = threadIdx.x;
    const int i0   = blockIdx.y * 128;
    const int j0   = blockIdx.x * 128;
    const int lane = t & 63, wid = t >> 6;
    const int wr = wid >> 1, wc = wid & 1;          // wave 2x2 over tile
    const int ln = lane & 15, ko = (lane >> 4) * 8; // fragment coords

    f32x4 acc[4][4];
#pragma unroll
    for (int m = 0; m < 4; ++m)
#pragma unroll
        for (int n = 0; n < 4; ++n) acc[m][n] = (f32x4){0.f, 0.f, 0.f, 0.f};

    const int row_s = t >> 2;            // staging: 4 threads per row
    const int kq_s  = (t & 3) * 8;       // 4 chunks of 8 bf16 = 32 k

    for (int k0 = 0; k0 < K; k0 += 32) {
#pragma unroll
        for (int l = 0; l < 2; ++l) {
            int row = row_s + l * 64;
            size_t ga = (size_t)(i0 + row) * K + k0 + kq_s;
            *(uint4*)&sA[0][row][kq_s] = *(const uint4*)&Ahi[ga];
            *(uint4*)&sA[1][row][kq_s] = *(const uint4*)&Alo[ga];
            size_t gb = (size_t)(j0 + row) * K + k0 + kq_s;
            *(uint4*)&sB[0][row][kq_s] = *(const uint4*)&Bhi[gb];
            *(uint4*)&sB[1][row][kq_s] = *(const uint4*)&Blo[gb];
        }
        __syncthreads();

        short8 ah[4], al[4];
#pragma unroll
        for (int m = 0; m < 4; ++m) {
            ah[m] = *(const short8*)&sA[0][wr * 64 + m * 16 + ln][ko];
            al[m] = *(const short8*)&sA[1][wr * 64 + m * 16 + ln][ko];
        }
#pragma unroll
        for (int n = 0; n < 4; ++n) {
            short8 bh = *(const short8*)&sB[0][wc * 64 + n * 16 + ln][ko];
            short8 bl = *(const short8*)&sB[1][wc * 64 + n * 16 + ln][ko];
#pragma unroll
            for (int m = 0; m < 4; ++m) {
                acc[m][n] = __builtin_amdgcn_mfma_f32_16x16x32_bf16(ah[m], bh, acc[m][n], 0, 0, 0);
                acc[m][n] = __builtin_amdgcn_mfma_f32_16x16x32_bf16(al[m], bh, acc[m][n], 0, 0, 0);
                acc[m][n] = __builtin_amdgcn_mfma_f32_16x16x32_bf16(ah[m], bl, acc[m][n], 0, 0, 0);
            }
        }
        __syncthreads();
    }

    // Epilogue: C/D layout (verified): col = lane&15, row = (lane>>4)*4 + r.
    const int chunk = 1 << cl;
#pragma unroll
    for (int n = 0; n < 4; ++n) {
        int j = j0 + wc * 64 + n * 16 + ln;
        int h = j >> cl, c = j & (chunk - 1);
        float bv = bias[j];
#pragma unroll
        for (int m = 0; m < 4; ++m) {
#pragma unroll
            for (int r = 0; r < 4; ++r) {
                int i  = i0 + wr * 64 + m * 16 + (lane >> 4) * 4 + r;
                int bb = i >> 9, s = i & 511;
                Cdst[((size_t)(bb * Hn + h) * SEQ + s) * chunk + c] = acc[m][n][r] + bv;
            }
        }
    }
}

// ---------------------------------------------------------------------------
// scores[b,h,i,j] = scale * dot(q[b,h,i,:], k[b,h,j,:]) + prev[b,h,i,j]
// ---------------------------------------------------------------------------
__global__ __launch_bounds__(256)
void scores_kernel(const float* __restrict__ q_ws, const float* __restrict__ k_ws,
                   const float* __restrict__ prev, const float* __restrict__ scale_p,
                   float* __restrict__ scores)
{
    const int bid   = blockIdx.x;
    const int batch = bid >> 6;
    const int tile  = bid & 63;
    const int i0    = (tile >> 3) * 64;
    const int j0    = (tile & 7) * 64;
    const float* q = q_ws + (size_t)batch * SEQ * HDIM;
    const float* k = k_ws + (size_t)batch * SEQ * HDIM;
    const float scale = *scale_p;

    __shared__ float sA[16][68];
    __shared__ float sB[16][68];
    const int t = threadIdx.x;
    const int ty = t >> 4, tx = t & 15;
    float acc[4][4] = {};

    for (int k0 = 0; k0 < HDIM; k0 += 16) {
        int row = t >> 2, c4 = (t & 3) * 4;
        float4 va = *(const float4*)&q[(size_t)(i0 + row) * HDIM + k0 + c4];
        sA[c4 + 0][row] = va.x; sA[c4 + 1][row] = va.y;
        sA[c4 + 2][row] = va.z; sA[c4 + 3][row] = va.w;
        float4 vb = *(const float4*)&k[(size_t)(j0 + row) * HDIM + k0 + c4];
        sB[c4 + 0][row] = vb.x; sB[c4 + 1][row] = vb.y;
        sB[c4 + 2][row] = vb.z; sB[c4 + 3][row] = vb.w;
        __syncthreads();
#pragma unroll
        for (int kk = 0; kk < 16; ++kk) {
            float4 a = *(const float4*)&sA[kk][ty * 4];
            float4 b = *(const float4*)&sB[kk][tx * 4];
            float ra[4] = {a.x, a.y, a.z, a.w};
            float rb[4] = {b.x, b.y, b.z, b.w};
#pragma unroll
            for (int x = 0; x < 4; ++x)
#pragma unroll
                for (int y = 0; y < 4; ++y) acc[x][y] += ra[x] * rb[y];
        }
        __syncthreads();
    }

#pragma unroll
    for (int x = 0; x < 4; ++x) {
        int i = i0 + ty * 4 + x;
        size_t base = ((size_t)batch * SEQ + i) * SEQ + j0 + tx * 4;
        float4 pv = *(const float4*)&prev[base];
        float4 r;
        r.x = acc[x][0] * scale + pv.x;
        r.y = acc[x][1] * scale + pv.y;
        r.z = acc[x][2] * scale + pv.z;
        r.w = acc[x][3] * scale + pv.w;
        *(float4*)&scores[base] = r;
    }
}

// ---------------------------------------------------------------------------
// Row softmax + gating: attn = g * softmax(scores, axis=-1). In-place on g.
// ---------------------------------------------------------------------------
__global__ __launch_bounds__(256)
void softmax_gate(const float* __restrict__ scores, float* __restrict__ attn)
{
    const int row = blockIdx.x * 4 + (threadIdx.x >> 6);
    const int l   = threadIdx.x & 63;
    const size_t base = (size_t)row * SEQ;

    float4 x0 = *(const float4*)&scores[base + l * 4];
    float4 x1 = *(const float4*)&scores[base + 256 + l * 4];
    float xs[8] = {x0.x, x0.y, x0.z, x0.w, x1.x, x1.y, x1.z, x1.w};

    float m = xs[0];
#pragma unroll
    for (int i = 1; i < 8; ++i) m = fmaxf(m, xs[i]);
#pragma unroll
    for (int o = 1; o < 64; o <<= 1) m = fmaxf(m, __shfl_xor(m, o));

    float es[8];
    float sum = 0.f;
#pragma unroll
    for (int i = 0; i < 8; ++i) { es[i] = __expf(xs[i] - m); sum += es[i]; }
#pragma unroll
    for (int o = 1; o < 64; o <<= 1) sum += __shfl_xor(sum, o);
    const float inv = 1.0f / sum;

    float4 g0 = *(const float4*)&attn[base + l * 4];
    float4 g1 = *(const float4*)&attn[base + 256 + l * 4];
    float4 r0, r1;
    r0.x = g0.x * es[0] * inv; r0.y = g0.y * es[1] * inv;
    r0.z = g0.z * es[2] * inv; r0.w = g0.w * es[3] * inv;
    r1.x = g1.x * es[4] * inv; r1.y = g1.y * es[5] * inv;
    r1.z = g1.z * es[6] * inv; r1.w = g1.w * es[7] * inv;
    *(float4*)&attn[base + l * 4]       = r0;
    *(float4*)&attn[base + 256 + l * 4] = r1;
}

// ---------------------------------------------------------------------------
// o[b,s,h,:] = attn[b,h,s,:] @ v[b,h,:,:]
// ---------------------------------------------------------------------------
__global__ __launch_bounds__(256)
void pv_kernel(const float* __restrict__ attn, const float* __restrict__ v_ws,
               float* __restrict__ o_ws)
{
    const int bid   = blockIdx.x;
    const int batch = bid >> 3;
    const int i0    = (bid & 7) * 64;
    const float* A = attn + (size_t)batch * SEQ * SEQ;
    const float* V = v_ws + (size_t)batch * SEQ * HDIM;
    const int b = batch >> 4, h = batch & 15;

    __shared__ float sA[16][68];
    __shared__ float sB[16][64];
    const int t = threadIdx.x;
    const int ty = t >> 4, tx = t & 15;
    float acc[4][4] = {};

    for (int k0 = 0; k0 < SEQ; k0 += 16) {
        int row = t >> 2, c4 = (t & 3) * 4;
        float4 va = *(const float4*)&A[(size_t)(i0 + row) * SEQ + k0 + c4];
        sA[c4 + 0][row] = va.x; sA[c4 + 1][row] = va.y;
        sA[c4 + 2][row] = va.z; sA[c4 + 3][row] = va.w;
        int r = t >> 4, c44 = (t & 15) * 4;
        *(float4*)&sB[r][c44] = *(const float4*)&V[(size_t)(k0 + r) * HDIM + c44];
        __syncthreads();
#pragma unroll
        for (int kk = 0; kk < 16; ++kk) {
            float4 a = *(const float4*)&sA[kk][ty * 4];
            float4 bv = *(const float4*)&sB[kk][tx * 4];
            float ra[4] = {a.x, a.y, a.z, a.w};
            float rb[4] = {bv.x, bv.y, bv.z, bv.w};
#pragma unroll
            for (int x = 0; x < 4; ++x)
#pragma unroll
                for (int y = 0; y < 4; ++y) acc[x][y] += ra[x] * rb[y];
        }
        __syncthreads();
    }

#pragma unroll
    for (int x = 0; x < 4; ++x) {
        int i = i0 + ty * 4 + x;
        size_t dst = ((size_t)(b * SEQ + i) * NH + h) * HDIM + tx * 4;
        float4 r = {acc[x][0], acc[x][1], acc[x][2], acc[x][3]};
        *(float4*)&o_ws[dst] = r;
    }
}

// ---------------------------------------------------------------------------
extern "C" void kernel_launch(void* const* d_in, const int* in_sizes, int n_in,
                              void* d_out, int out_size, void* d_ws, size_t ws_size,
                              hipStream_t stream)
{
    const float* Q     = (const float*)d_in[0];
    const float* prev  = (const float*)d_in[1];
    const float* Wq    = (const float*)d_in[2];
    const float* bq    = (const float*)d_in[3];
    const float* Wk    = (const float*)d_in[4];
    const float* bk    = (const float*)d_in[5];
    const float* Wv    = (const float*)d_in[6];
    const float* bv    = (const float*)d_in[7];
    const float* Wg    = (const float*)d_in[8];
    const float* bg    = (const float*)d_in[9];
    const float* Wo    = (const float*)d_in[10];
    const float* bo    = (const float*)d_in[11];
    const float* scale = (const float*)d_in[12];

    float* out    = (float*)d_out;                 // [B,S,D]
    float* attn   = out + OUT_ELEMS;               // [B,H,S,S] (holds g temporarily)
    float* scores = attn + ATTN_ELEMS;             // [B,H,S,S]

    float* q_ws = (float*)d_ws;                    // [B,H,S,DK] 32 MiB
    float* k_ws = q_ws + OUT_ELEMS;
    float* v_ws = k_ws + OUT_ELEMS;
    float* o_ws = q_ws;                            // q dead after scores_kernel

    // bf16 scratch lives in the scores region (dead until scores_kernel):
    const size_t U1M = 1048576;                    // 1M ushorts = 2 MiB
    ushort* sc16 = (ushort*)scores;
    ushort* WtQh = sc16 + 0 * U1M;
    ushort* WtQl = sc16 + 1 * U1M;
    ushort* WtKh = sc16 + 2 * U1M;
    ushort* WtKl = sc16 + 3 * U1M;
    ushort* WtVh = sc16 + 4 * U1M;
    ushort* WtVl = sc16 + 5 * U1M;
    ushort* WtGh = sc16 + 6 * U1M;                 // 8192x1024 = 8M ushorts
    ushort* WtGl = sc16 + 14 * U1M;
    ushort* Qh   = sc16 + 22 * U1M;                // 8192x1024
    ushort* Ql   = sc16 + 30 * U1M;                // ends at 76 MiB < 256 MiB

    // o/Wo splits happen after k_ws/v_ws die:
    ushort* Oh   = (ushort*)k_ws;                  // free after scores_kernel
    ushort* Ol   = Oh + OUT_ELEMS;
    ushort* WtOh = (ushort*)v_ws;                  // free after pv_kernel
    ushort* WtOl = WtOh + U1M;

    dim3 blk(256);

    // split inputs to bf16 hi/lo
    splitT_kernel<<<dim3(16, 16), blk, 0, stream>>>(Wq, WtQh, WtQl, DMODEL, DMODEL);
    splitT_kernel<<<dim3(16, 16), blk, 0, stream>>>(Wk, WtKh, WtKl, DMODEL, DMODEL);
    splitT_kernel<<<dim3(16, 16), blk, 0, stream>>>(Wv, WtVh, WtVl, DMODEL, DMODEL);
    splitT_kernel<<<dim3(128, 16), blk, 0, stream>>>(Wg, WtGh, WtGl, 8192, DMODEL);
    split_kernel<<<4096, blk, 0, stream>>>(Q, Qh, Ql);

    // projections -> [B,H,S,DK]  (MFMA bf16x3)
    gemm_mfma<<<dim3(8, 64), blk, 0, stream>>>(Qh, Ql, WtQh, WtQl, bq, q_ws, DMODEL, NH, 6);
    gemm_mfma<<<dim3(8, 64), blk, 0, stream>>>(Qh, Ql, WtKh, WtKl, bk, k_ws, DMODEL, NH, 6);
    gemm_mfma<<<dim3(8, 64), blk, 0, stream>>>(Qh, Ql, WtVh, WtVl, bv, v_ws, DMODEL, NH, 6);
    // gating GEMM -> g stored in attn slot as [B,H,S,S]
    gemm_mfma<<<dim3(64, 64), blk, 0, stream>>>(Qh, Ql, WtGh, WtGl, bg, attn, DMODEL, NH, 9);

    // scores = scale*q.k^T + prev  (kills the bf16 scratch in scores slot)
    scores_kernel<<<256 * 64, blk, 0, stream>>>(q_ws, k_ws, prev, scale, scores);
    // attn = g * softmax(scores)
    softmax_gate<<<(16 * NH * SEQ) / 4, blk, 0, stream>>>(scores, attn);
    // o = attn @ v -> [B,S,D] (into q_ws)
    pv_kernel<<<256 * 8, blk, 0, stream>>>(attn, v_ws, o_ws);

    // out = o @ Wo + bo  (MFMA bf16x3; o split into dead k_ws, Wo^T into dead v_ws)
    split_kernel<<<4096, blk, 0, stream>>>(o_ws, Oh, Ol);
    splitT_kernel<<<dim3(16, 16), blk, 0, stream>>>(Wo, WtOh, WtOl, DMODEL, DMODEL);
    gemm_mfma<<<dim3(8, 64), blk, 0, stream>>>(Oh, Ol, WtOh, WtOl, bo, out, DMODEL, 1, 10);
}